// Round 1
// baseline (168.666 us; speedup 1.0000x reference)
//
#include <hip/hip_runtime.h>

#define N_ELEM   8388608
#define NGROUPS  1024
#define EPSF     1e-9f
#define MAX_ITERS 30

// ---- monotone float<->uint mapping for atomicMin/Max on floats ----
__device__ __forceinline__ unsigned enc_f(float f) {
    unsigned u = __float_as_uint(f);
    return (u & 0x80000000u) ? ~u : (u | 0x80000000u);
}
__device__ __forceinline__ float dec_f(unsigned e) {
    unsigned u = (e & 0x80000000u) ? (e ^ 0x80000000u) : ~e;
    return __uint_as_float(u);
}

// ---- kernel 0: init per-group accumulators (ws is poisoned 0xAA each launch) ----
__global__ __launch_bounds__(NGROUPS) void k_init(float* gsum, unsigned* gcnt,
                                                  unsigned* gmn, unsigned* gmx) {
    int g = threadIdx.x;
    gsum[g] = 0.0f;
    gcnt[g] = 0u;
    gmn[g]  = 0xFFFFFFFFu;
    gmx[g]  = 0u;
}

// ---- kernel A: stream inputs once; write y_clipped; accumulate group stats ----
__global__ __launch_bounds__(1024) void k_stats(const float4* __restrict__ yraw4,
                                                const float4* __restrict__ yreal4,
                                                const int4*   __restrict__ gid4,
                                                float4*       __restrict__ out4,
                                                float* gsum, unsigned* gcnt,
                                                unsigned* gmn, unsigned* gmx, int n4) {
    __shared__ float    s_sum[NGROUPS];
    __shared__ unsigned s_cnt[NGROUPS];
    __shared__ unsigned s_mn[NGROUPS];
    __shared__ unsigned s_mx[NGROUPS];
    int t = threadIdx.x;
    for (int g = t; g < NGROUPS; g += blockDim.x) {
        s_sum[g] = 0.0f; s_cnt[g] = 0u; s_mn[g] = 0xFFFFFFFFu; s_mx[g] = 0u;
    }
    __syncthreads();

    int stride = gridDim.x * blockDim.x;
    for (int i = blockIdx.x * blockDim.x + t; i < n4; i += stride) {
        float4 yr = yraw4[i];
        float4 ye = yreal4[i];
        int4   gg = gid4[i];
        float yrs[4] = { yr.x, yr.y, yr.z, yr.w };
        float yes[4] = { ye.x, ye.y, ye.z, ye.w };
        int   gs[4]  = { gg.x, gg.y, gg.z, gg.w };
        float oc[4];
#pragma unroll
        for (int j = 0; j < 4; ++j) {
            float yraw = yrs[j];
            float yrc  = fmaxf(yes[j], EPSF);
            float l = 0.9f * yrc;
            float u = 1.1f * yrc;
            float yclip = fminf(fmaxf(yraw, l), u);
            oc[j] = yclip;
            float w = 1.0f / yrc;          // == 1/max(y_real,1e-9) of the reference
            float s  = w * yclip;
            float a0 = (l - yraw) * w;     // bracket endpoints, exact ref fp32 ops
            float a1 = (u - yraw) * w;
            int g = gs[j];
            atomicAdd(&s_sum[g], s);
            atomicAdd(&s_cnt[g], 1u);
            atomicMin(&s_mn[g], enc_f(a0));
            atomicMax(&s_mx[g], enc_f(a1));
        }
        out4[i] = make_float4(oc[0], oc[1], oc[2], oc[3]);
    }
    __syncthreads();
    for (int g = t; g < NGROUPS; g += blockDim.x) {
        atomicAdd(&gsum[g], s_sum[g]);
        atomicAdd(&gcnt[g], s_cnt[g]);
        atomicMin(&gmn[g], s_mn[g]);
        atomicMax(&gmx[g], s_mx[g]);
    }
}

// ---- kernel B: per-group scalars (feasible, T, brackets) + compaction offsets ----
__global__ __launch_bounds__(NGROUPS) void k_group(const float* gsum, const unsigned* gcnt,
                                                   const unsigned* gmn, const unsigned* gmx,
                                                   unsigned* feas, float* gT, float* glo,
                                                   float* ghi, float* galpha, unsigned* gbase,
                                                   unsigned* gcur, unsigned* total) {
    __shared__ unsigned s_scan[NGROUPS];
    int g = threadIdx.x;
    unsigned c = gcnt[g];
    float n  = (float)c;
    float S0 = gsum[g];
    float L = 0.95f * n;
    float U = 1.05f * n;
    unsigned f = (S0 >= L && S0 <= U) ? 1u : 0u;
    float alo, ahi;
    if (c == 0u) { alo = 0.0f; ahi = 0.0f; }
    else { alo = dec_f(gmn[g]) - 1.0f; ahi = dec_f(gmx[g]) + 1.0f; }
    feas[g]   = f;
    gT[g]     = (S0 < L) ? L : U;
    glo[g]    = alo;
    ghi[g]    = ahi;
    galpha[g] = 0.0f;   // feasible groups: alpha=0 -> clip(y_raw+0/w,l,u) == y_clipped

    unsigned v = f ? 0u : c;
    s_scan[g] = v;
    for (int off = 1; off < NGROUPS; off <<= 1) {
        __syncthreads();
        unsigned tmp = (g >= off) ? s_scan[g - off] : 0u;
        __syncthreads();
        s_scan[g] += tmp;
    }
    __syncthreads();
    unsigned incl = s_scan[g];
    unsigned base = incl - v;
    gbase[g] = base;
    gcur[g]  = base;
    if (g == NGROUPS - 1) *total = incl;
}

// ---- kernel C: compact indices of elements in infeasible groups ----
__global__ __launch_bounds__(256) void k_compact(const int4* __restrict__ gid4,
                                                 const unsigned* __restrict__ feas,
                                                 unsigned* gcur, const unsigned* total,
                                                 unsigned* cidx, unsigned* cgid,
                                                 unsigned capacity, int n4) {
    if (*total == 0u) return;          // expected path: exit before touching gid
    __shared__ unsigned s_feas[NGROUPS];
    for (int g = threadIdx.x; g < NGROUPS; g += blockDim.x) s_feas[g] = feas[g];
    __syncthreads();
    int stride = gridDim.x * blockDim.x;
    for (int i = blockIdx.x * blockDim.x + threadIdx.x; i < n4; i += stride) {
        int4 gg = gid4[i];
        int gs[4] = { gg.x, gg.y, gg.z, gg.w };
#pragma unroll
        for (int j = 0; j < 4; ++j) {
            int g = gs[j];
            if (!s_feas[g]) {
                unsigned pos = atomicAdd(&gcur[g], 1u);
                if (pos < capacity) {
                    cidx[pos] = (unsigned)(4 * i + j);
                    cgid[pos] = (unsigned)g;
                }
            }
        }
    }
}

// ---- kernel D: per-group bisection (one block per group, LDS-cached data) ----
#define CAPC 8064   // float2 cache: 64512 B, fits 64KB static LDS with extras
__global__ __launch_bounds__(256) void k_bisect(const float* __restrict__ y_raw,
                                                const float* __restrict__ y_real,
                                                const unsigned* feas, const unsigned* gcnt,
                                                const unsigned* gbase, const float* gT,
                                                const float* glo_a, const float* ghi_a,
                                                float* galpha, const unsigned* __restrict__ cidx,
                                                unsigned capacity) {
    int g = blockIdx.x;
    if (feas[g]) return;
    __shared__ float2 cache[CAPC];
    __shared__ double s_part[4];
    __shared__ float  s_mid;
    unsigned base = gbase[g];
    unsigned cnt  = gcnt[g];
    if (base >= capacity) cnt = 0;
    else if (cnt > capacity - base) cnt = capacity - base;
    int t = threadIdx.x;
    for (unsigned i = t; i < cnt && i < CAPC; i += 256u) {
        unsigned idx = cidx[base + i];
        cache[i] = make_float2(y_raw[idx], y_real[idx]);
    }
    __syncthreads();
    float lo = glo_a[g], hi = ghi_a[g], T = gT[g];
    float mid = lo;
    for (int it = 0; it < MAX_ITERS; ++it) {
        if (t == 0) s_mid = 0.5f * (lo + hi);
        __syncthreads();
        float m = s_mid;
        double part = 0.0;
        for (unsigned i = t; i < cnt; i += 256u) {
            float yraw, ye;
            if (i < CAPC) { float2 v = cache[i]; yraw = v.x; ye = v.y; }
            else { unsigned idx = cidx[base + i]; yraw = y_raw[idx]; ye = y_real[idx]; }
            float yrc = fmaxf(ye, EPSF);
            float l = 0.9f * yrc;
            float u = 1.1f * yrc;
            float w = 1.0f / yrc;
            float ym = fminf(fmaxf(yraw + m / w, l), u);   // ref: clip(y_raw + mid/w, l, u)
            part += (double)(w * ym);
        }
#pragma unroll
        for (int off = 32; off > 0; off >>= 1) part += __shfl_down(part, off, 64);
        if ((t & 63) == 0) s_part[t >> 6] = part;
        __syncthreads();
        if (t == 0) {
            float Smid = (float)(s_part[0] + s_part[1] + s_part[2] + s_part[3]);
            if (Smid < T) lo = m; else hi = m;
        }
        mid = m;
        __syncthreads();
    }
    if (t == 0) galpha[g] = mid;   // ref returns the LAST mid, not 0.5*(lo+hi)
}

// ---- kernel E: fix up infeasible-group elements with y_bis ----
__global__ __launch_bounds__(256) void k_fixup(const float* __restrict__ y_raw,
                                               const float* __restrict__ y_real,
                                               const unsigned* __restrict__ cidx,
                                               const unsigned* __restrict__ cgid,
                                               const float* galpha, const unsigned* total,
                                               float* __restrict__ out, unsigned capacity) {
    unsigned tot = *total;
    if (tot > capacity) tot = capacity;
    unsigned stride = gridDim.x * blockDim.x;
    for (unsigned i = blockIdx.x * blockDim.x + threadIdx.x; i < tot; i += stride) {
        unsigned idx = cidx[i];
        unsigned g   = cgid[i];
        float yraw = y_raw[idx];
        float yrc  = fmaxf(y_real[idx], EPSF);
        float l = 0.9f * yrc;
        float u = 1.1f * yrc;
        float w = 1.0f / yrc;
        float a = galpha[g];
        out[idx] = fminf(fmaxf(yraw + a / w, l), u);
    }
}

extern "C" void kernel_launch(void* const* d_in, const int* in_sizes, int n_in,
                              void* d_out, int out_size, void* d_ws, size_t ws_size,
                              hipStream_t stream) {
    const float* y_raw  = (const float*)d_in[0];
    const float* y_real = (const float*)d_in[1];
    const int*   gid    = (const int*)d_in[2];
    float* out = (float*)d_out;
    const int n  = in_sizes[0];      // 8388608
    const int n4 = n / 4;

    char* ws = (char*)d_ws;
    float*    gsum   = (float*)(ws + 0);
    unsigned* gcnt   = (unsigned*)(ws + 4096);
    unsigned* gmn    = (unsigned*)(ws + 8192);
    unsigned* gmx    = (unsigned*)(ws + 12288);
    unsigned* feas   = (unsigned*)(ws + 16384);
    float*    gT     = (float*)(ws + 20480);
    float*    glo    = (float*)(ws + 24576);
    float*    ghi    = (float*)(ws + 28672);
    float*    galpha = (float*)(ws + 32768);
    unsigned* gbase  = (unsigned*)(ws + 36864);
    unsigned* gcur   = (unsigned*)(ws + 40960);
    unsigned* total  = (unsigned*)(ws + 45056);
    unsigned* cidx   = (unsigned*)(ws + 49152);
    size_t cap64 = (ws_size > 49152) ? (ws_size - 49152) / 8 : 0;
    if (cap64 > (size_t)n) cap64 = (size_t)n;
    unsigned capacity = (unsigned)cap64;
    unsigned* cgid = cidx + capacity;

    k_init<<<1, NGROUPS, 0, stream>>>(gsum, gcnt, gmn, gmx);
    k_stats<<<256, 1024, 0, stream>>>((const float4*)y_raw, (const float4*)y_real,
                                      (const int4*)gid, (float4*)out,
                                      gsum, gcnt, gmn, gmx, n4);
    k_group<<<1, NGROUPS, 0, stream>>>(gsum, gcnt, gmn, gmx, feas, gT, glo, ghi,
                                       galpha, gbase, gcur, total);
    k_compact<<<512, 256, 0, stream>>>((const int4*)gid, feas, gcur, total,
                                       cidx, cgid, capacity, n4);
    k_bisect<<<NGROUPS, 256, 0, stream>>>(y_raw, y_real, feas, gcnt, gbase, gT,
                                          glo, ghi, galpha, cidx, capacity);
    k_fixup<<<512, 256, 0, stream>>>(y_raw, y_real, cidx, cgid, galpha, total,
                                     out, capacity);
}

// Round 2
// 150.679 us; speedup vs baseline: 1.1194x; 1.1194x over previous
//
#include <hip/hip_runtime.h>

#define NGROUPS  1024
#define EPSF     1e-9f
#define MAX_ITERS 30
#define SUM_MASK ((1ull << 49) - 1)
#define CNT_SHIFT 49
#define FIX_SCALE 1073741824.0f      // 2^30
#define FIX_INV   (1.0 / 1073741824.0)

// ---- monotone float<->uint mapping for atomicMin/Max on floats ----
__device__ __forceinline__ unsigned enc_f(float f) {
    unsigned u = __float_as_uint(f);
    return (u & 0x80000000u) ? ~u : (u | 0x80000000u);
}
__device__ __forceinline__ float dec_f(unsigned e) {
    unsigned u = (e & 0x80000000u) ? (e ^ 0x80000000u) : ~e;
    return __uint_as_float(u);
}

// ---- kernel 0: init per-group accumulators (ws is poisoned 0xAA each launch) ----
__global__ __launch_bounds__(NGROUPS) void k_init(unsigned long long* gpack,
                                                  unsigned* gmn, unsigned* gmx) {
    int g = threadIdx.x;
    gpack[g] = 0ull;
    gmn[g]   = 0xFFFFFFFFu;
    gmx[g]   = 0u;
}

// ---- kernel A: stream inputs once; write y_clipped; packed (cnt|sum) histo ----
// grid: ceil(n4/4096) blocks x 1024 threads, each thread owns 4 float4 tiles.
__global__ __launch_bounds__(1024) void k_stats(const float4* __restrict__ yraw4,
                                                const float4* __restrict__ yreal4,
                                                const int4*   __restrict__ gid4,
                                                float4*       __restrict__ out4,
                                                unsigned long long* gpack, int n4) {
    __shared__ unsigned long long s_pk[NGROUPS];
    int t = threadIdx.x;
    s_pk[t] = 0ull;                       // blockDim.x == NGROUPS == 1024
    __syncthreads();

    int base = blockIdx.x * 4096;
    float4 yr[4], ye[4];
    int4   gg[4];
    bool   ok[4];
#pragma unroll
    for (int k = 0; k < 4; ++k) {         // issue all 12 loads up front (MLP)
        int i = base + k * 1024 + t;
        ok[k] = (i < n4);
        if (ok[k]) { yr[k] = yraw4[i]; ye[k] = yreal4[i]; gg[k] = gid4[i]; }
    }
#pragma unroll
    for (int k = 0; k < 4; ++k) {
        if (!ok[k]) continue;
        float yrs[4] = { yr[k].x, yr[k].y, yr[k].z, yr[k].w };
        float yes[4] = { ye[k].x, ye[k].y, ye[k].z, ye[k].w };
        int   gs[4]  = { gg[k].x, gg[k].y, gg[k].z, gg[k].w };
        float oc[4];
#pragma unroll
        for (int j = 0; j < 4; ++j) {
            float yraw = yrs[j];
            float yrc  = fmaxf(yes[j], EPSF);
            float l = 0.9f * yrc;
            float u = 1.1f * yrc;
            float yclip = fminf(fmaxf(yraw, l), u);
            oc[j] = yclip;
            float s = yclip / yrc;                      // in [0.9, 1.1] always
            unsigned long long pk = (1ull << CNT_SHIFT)
                + (unsigned long long)__float2uint_rn(s * FIX_SCALE);
            atomicAdd(&s_pk[gs[j]], pk);
        }
        out4[base + k * 1024 + t] = make_float4(oc[0], oc[1], oc[2], oc[3]);
    }
    __syncthreads();
    if (s_pk[t] != 0ull) atomicAdd(&gpack[t], s_pk[t]);
}

// ---- kernel B: per-group scalars (feasible, T) + compaction offsets ----
__global__ __launch_bounds__(NGROUPS) void k_group(const unsigned long long* gpack,
                                                   unsigned* feas, float* gT,
                                                   float* galpha, unsigned* gbase,
                                                   unsigned* gcur, unsigned* total) {
    __shared__ unsigned s_scan[NGROUPS];
    int g = threadIdx.x;
    unsigned long long pk = gpack[g];
    unsigned c = (unsigned)(pk >> CNT_SHIFT);
    float S0 = (float)((double)(pk & SUM_MASK) * FIX_INV);
    float n  = (float)c;
    float L = 0.95f * n;
    float U = 1.05f * n;
    unsigned f = (S0 >= L && S0 <= U) ? 1u : 0u;
    feas[g]   = f;
    gT[g]     = (S0 < L) ? L : U;
    galpha[g] = 0.0f;   // feasible groups: alpha=0 -> y_clipped (already in out)

    unsigned v = f ? 0u : c;
    s_scan[g] = v;
    for (int off = 1; off < NGROUPS; off <<= 1) {
        __syncthreads();
        unsigned tmp = (g >= off) ? s_scan[g - off] : 0u;
        __syncthreads();
        s_scan[g] += tmp;
    }
    __syncthreads();
    unsigned incl = s_scan[g];
    unsigned base = incl - v;
    gbase[g] = base;
    gcur[g]  = base;
    if (g == NGROUPS - 1) *total = incl;
}

// ---- kernel C (rare path): bracket min/max + index compaction, fused ----
__global__ __launch_bounds__(256) void k_mmc(const float4* __restrict__ yraw4,
                                             const float4* __restrict__ yreal4,
                                             const int4*   __restrict__ gid4,
                                             const unsigned* __restrict__ feas,
                                             unsigned* gcur, const unsigned* total,
                                             unsigned* gmn, unsigned* gmx,
                                             unsigned* cidx, unsigned* cgid,
                                             unsigned capacity, int n4) {
    if (*total == 0u) return;           // expected path: exit immediately
    __shared__ unsigned s_feas[NGROUPS];
    __shared__ unsigned s_mn[NGROUPS];
    __shared__ unsigned s_mx[NGROUPS];
    for (int g = threadIdx.x; g < NGROUPS; g += blockDim.x) {
        s_feas[g] = feas[g]; s_mn[g] = 0xFFFFFFFFu; s_mx[g] = 0u;
    }
    __syncthreads();
    int stride = gridDim.x * blockDim.x;
    for (int i = blockIdx.x * blockDim.x + threadIdx.x; i < n4; i += stride) {
        int4 gg = gid4[i];
        int gs[4] = { gg.x, gg.y, gg.z, gg.w };
        bool any = !s_feas[gs[0]] || !s_feas[gs[1]] || !s_feas[gs[2]] || !s_feas[gs[3]];
        if (!any) continue;
        float4 yr = yraw4[i];
        float4 ye = yreal4[i];
        float yrs[4] = { yr.x, yr.y, yr.z, yr.w };
        float yes[4] = { ye.x, ye.y, ye.z, ye.w };
#pragma unroll
        for (int j = 0; j < 4; ++j) {
            int g = gs[j];
            if (s_feas[g]) continue;
            float yraw = yrs[j];
            float yrc  = fmaxf(yes[j], EPSF);
            float l = 0.9f * yrc;
            float u = 1.1f * yrc;
            float w = 1.0f / yrc;
            float a0 = (l - yraw) * w;   // exact ref fp32 ops -> bitwise bracket
            float a1 = (u - yraw) * w;
            atomicMin(&s_mn[g], enc_f(a0));
            atomicMax(&s_mx[g], enc_f(a1));
            unsigned pos = atomicAdd(&gcur[g], 1u);
            if (pos < capacity) {
                cidx[pos] = (unsigned)(4 * i + j);
                cgid[pos] = (unsigned)g;
            }
        }
    }
    __syncthreads();
    for (int g = threadIdx.x; g < NGROUPS; g += blockDim.x) {
        if (!s_feas[g]) {
            atomicMin(&gmn[g], s_mn[g]);
            atomicMax(&gmx[g], s_mx[g]);
        }
    }
}

// ---- kernel D: per-group bisection (one block per group, LDS-cached data) ----
#define CAPC 8064   // float2 cache: 64512 B
__global__ __launch_bounds__(256) void k_bisect(const float* __restrict__ y_raw,
                                                const float* __restrict__ y_real,
                                                const unsigned* feas,
                                                const unsigned long long* gpack,
                                                const unsigned* gbase, const float* gT,
                                                const unsigned* gmn, const unsigned* gmx,
                                                float* galpha,
                                                const unsigned* __restrict__ cidx,
                                                unsigned capacity) {
    int g = blockIdx.x;
    if (feas[g]) return;
    __shared__ float2 cache[CAPC];
    __shared__ double s_part[4];
    __shared__ float  s_mid;
    unsigned base = gbase[g];
    unsigned cnt  = (unsigned)(gpack[g] >> CNT_SHIFT);
    if (base >= capacity) cnt = 0;
    else if (cnt > capacity - base) cnt = capacity - base;
    int t = threadIdx.x;
    for (unsigned i = t; i < cnt && i < CAPC; i += 256u) {
        unsigned idx = cidx[base + i];
        cache[i] = make_float2(y_raw[idx], y_real[idx]);
    }
    __syncthreads();
    float lo = dec_f(gmn[g]) - 1.0f;     // ref: segment_min(...) - 1
    float hi = dec_f(gmx[g]) + 1.0f;     // ref: segment_max(...) + 1
    float T  = gT[g];
    float mid = lo;
    for (int it = 0; it < MAX_ITERS; ++it) {
        if (t == 0) s_mid = 0.5f * (lo + hi);
        __syncthreads();
        float m = s_mid;
        double part = 0.0;
        for (unsigned i = t; i < cnt; i += 256u) {
            float yraw, ye;
            if (i < CAPC) { float2 v = cache[i]; yraw = v.x; ye = v.y; }
            else { unsigned idx = cidx[base + i]; yraw = y_raw[idx]; ye = y_real[idx]; }
            float yrc = fmaxf(ye, EPSF);
            float l = 0.9f * yrc;
            float u = 1.1f * yrc;
            float w = 1.0f / yrc;
            float ym = fminf(fmaxf(yraw + m / w, l), u);   // ref: clip(y_raw+mid/w,l,u)
            part += (double)(w * ym);
        }
#pragma unroll
        for (int off = 32; off > 0; off >>= 1) part += __shfl_down(part, off, 64);
        if ((t & 63) == 0) s_part[t >> 6] = part;
        __syncthreads();
        if (t == 0) {
            float Smid = (float)(s_part[0] + s_part[1] + s_part[2] + s_part[3]);
            if (Smid < T) lo = m; else hi = m;
        }
        mid = m;
        __syncthreads();
    }
    if (t == 0) galpha[g] = mid;   // ref returns the LAST mid
}

// ---- kernel E: fix up infeasible-group elements with y_bis ----
__global__ __launch_bounds__(256) void k_fixup(const float* __restrict__ y_raw,
                                               const float* __restrict__ y_real,
                                               const unsigned* __restrict__ cidx,
                                               const unsigned* __restrict__ cgid,
                                               const float* galpha, const unsigned* total,
                                               float* __restrict__ out, unsigned capacity) {
    unsigned tot = *total;
    if (tot > capacity) tot = capacity;
    unsigned stride = gridDim.x * blockDim.x;
    for (unsigned i = blockIdx.x * blockDim.x + threadIdx.x; i < tot; i += stride) {
        unsigned idx = cidx[i];
        unsigned g   = cgid[i];
        float yraw = y_raw[idx];
        float yrc  = fmaxf(y_real[idx], EPSF);
        float l = 0.9f * yrc;
        float u = 1.1f * yrc;
        float w = 1.0f / yrc;
        float a = galpha[g];
        out[idx] = fminf(fmaxf(yraw + a / w, l), u);
    }
}

extern "C" void kernel_launch(void* const* d_in, const int* in_sizes, int n_in,
                              void* d_out, int out_size, void* d_ws, size_t ws_size,
                              hipStream_t stream) {
    const float* y_raw  = (const float*)d_in[0];
    const float* y_real = (const float*)d_in[1];
    const int*   gid    = (const int*)d_in[2];
    float* out = (float*)d_out;
    const int n  = in_sizes[0];      // 8388608
    const int n4 = n / 4;

    char* ws = (char*)d_ws;
    unsigned long long* gpack = (unsigned long long*)(ws + 0);       // 8 KB
    unsigned* gmn    = (unsigned*)(ws + 8192);
    unsigned* gmx    = (unsigned*)(ws + 12288);
    unsigned* feas   = (unsigned*)(ws + 16384);
    float*    gT     = (float*)(ws + 20480);
    float*    galpha = (float*)(ws + 24576);
    unsigned* gbase  = (unsigned*)(ws + 28672);
    unsigned* gcur   = (unsigned*)(ws + 32768);
    unsigned* total  = (unsigned*)(ws + 36864);
    unsigned* cidx   = (unsigned*)(ws + 40960);
    size_t cap64 = (ws_size > 40960) ? (ws_size - 40960) / 8 : 0;
    if (cap64 > (size_t)n) cap64 = (size_t)n;
    unsigned capacity = (unsigned)cap64;
    unsigned* cgid = cidx + capacity;

    int nb_stats = (n4 + 4095) / 4096;   // 512 for N=8.4M -> 2 blocks/CU

    k_init<<<1, NGROUPS, 0, stream>>>(gpack, gmn, gmx);
    k_stats<<<nb_stats, 1024, 0, stream>>>((const float4*)y_raw, (const float4*)y_real,
                                           (const int4*)gid, (float4*)out, gpack, n4);
    k_group<<<1, NGROUPS, 0, stream>>>(gpack, feas, gT, galpha, gbase, gcur, total);
    k_mmc<<<512, 256, 0, stream>>>((const float4*)y_raw, (const float4*)y_real,
                                   (const int4*)gid, feas, gcur, total,
                                   gmn, gmx, cidx, cgid, capacity, n4);
    k_bisect<<<NGROUPS, 256, 0, stream>>>(y_raw, y_real, feas, gpack, gbase, gT,
                                          gmn, gmx, galpha, cidx, capacity);
    k_fixup<<<512, 256, 0, stream>>>(y_raw, y_real, cidx, cgid, galpha, total,
                                     out, capacity);
}